// Round 1
// baseline (278.082 us; speedup 1.0000x reference)
//
#include <hip/hip_runtime.h>
#include <hip/hip_bf16.h>

#define BB 16
#define NI 2048
#define NA 2048
#define DD 256

typedef __attribute__((ext_vector_type(8))) short short8;   // 8 bf16 = 4 VGPR
typedef __attribute__((ext_vector_type(4))) float f32x4;

static __device__ __forceinline__ unsigned short f2bf(float f) {
  union { float f; unsigned int u; } x; x.f = f;
  unsigned int r = x.u + 0x7fffu + ((x.u >> 16) & 1u);   // RNE
  return (unsigned short)(r >> 16);
}
static __device__ __forceinline__ float bf2f(unsigned short h) {
  union { unsigned int u; float f; } x; x.u = ((unsigned int)h) << 16;
  return x.f;
}

// ---------------- split attendee into hi/lo bf16 ----------------
__global__ void split_kernel(const float* __restrict__ a,
                             unsigned short* __restrict__ hi,
                             unsigned short* __restrict__ lo) {
  const size_t N4 = (size_t)BB * NA * DD / 4;
  size_t stride = (size_t)gridDim.x * blockDim.x;
  for (size_t i = blockIdx.x * (size_t)blockDim.x + threadIdx.x; i < N4; i += stride) {
    float4 v = ((const float4*)a)[i];
    ushort4 h, l;
    h.x = f2bf(v.x); l.x = f2bf(v.x - bf2f(h.x));
    h.y = f2bf(v.y); l.y = f2bf(v.y - bf2f(h.y));
    h.z = f2bf(v.z); l.z = f2bf(v.z - bf2f(h.z));
    h.w = f2bf(v.w); l.w = f2bf(v.w - bf2f(h.w));
    ((ushort4*)hi)[i] = h;
    ((ushort4*)lo)[i] = l;
  }
}

// ---------------- transpose attendee (hi only) -> vt[b][d][j] ----------------
__global__ void tv_kernel(const float* __restrict__ a, unsigned short* __restrict__ vt) {
  __shared__ float t[64][65];
  int bx = blockIdx.x;
  int b = bx >> 7;            // 128 tiles per batch
  int r = bx & 127;
  int jt = r >> 2, dt = r & 3;
  int j0 = jt * 64, d0 = dt * 64;
  int tid = threadIdx.x;
  int rr = tid >> 4, c4 = (tid & 15) * 4;
#pragma unroll
  for (int k = 0; k < 4; ++k) {
    int row = rr + k * 16;
    float4 v = *(const float4*)(a + ((size_t)b * NA + j0 + row) * DD + d0 + c4);
    t[row][c4 + 0] = v.x; t[row][c4 + 1] = v.y; t[row][c4 + 2] = v.z; t[row][c4 + 3] = v.w;
  }
  __syncthreads();
#pragma unroll
  for (int k = 0; k < 4; ++k) {
    int d = rr + k * 16;
    ushort4 o;
    o.x = f2bf(t[c4 + 0][d]); o.y = f2bf(t[c4 + 1][d]);
    o.z = f2bf(t[c4 + 2][d]); o.w = f2bf(t[c4 + 3][d]);
    *(ushort4*)(vt + ((size_t)b * DD + d0 + d) * NA + j0 + c4) = o;
  }
}

// ---------------- transpose + split W -> wt[e][d] hi/lo ----------------
__global__ void tw_kernel(const float* __restrict__ w,
                          unsigned short* __restrict__ wthi,
                          unsigned short* __restrict__ wtlo) {
  __shared__ float t[64][65];
  int bx = blockIdx.x;
  int dt = bx >> 2, et = bx & 3;
  int d0 = dt * 64, e0 = et * 64;
  int tid = threadIdx.x;
  int rr = tid >> 4, c4 = (tid & 15) * 4;
#pragma unroll
  for (int k = 0; k < 4; ++k) {
    int row = rr + k * 16;   // d index
    float4 v = *(const float4*)(w + (size_t)(d0 + row) * DD + e0 + c4);
    t[row][c4 + 0] = v.x; t[row][c4 + 1] = v.y; t[row][c4 + 2] = v.z; t[row][c4 + 3] = v.w;
  }
  __syncthreads();
#pragma unroll
  for (int k = 0; k < 4; ++k) {
    int e = rr + k * 16;
    ushort4 h, l;
    float v0 = t[c4 + 0][e]; h.x = f2bf(v0); l.x = f2bf(v0 - bf2f(h.x));
    float v1 = t[c4 + 1][e]; h.y = f2bf(v1); l.y = f2bf(v1 - bf2f(h.y));
    float v2 = t[c4 + 2][e]; h.z = f2bf(v2); l.z = f2bf(v2 - bf2f(h.z));
    float v3 = t[c4 + 3][e]; h.w = f2bf(v3); l.w = f2bf(v3 - bf2f(h.w));
    *(ushort4*)(wthi + (size_t)(e0 + e) * DD + d0 + c4) = h;
    *(ushort4*)(wtlo + (size_t)(e0 + e) * DD + d0 + c4) = l;
  }
}

// ---------------- Q = x @ W  (split-bf16 MFMA), writes qhi/qlo ----------------
__global__ __launch_bounds__(256, 2) void qgemm_kernel(
    const float* __restrict__ x, const unsigned short* __restrict__ wthi,
    const unsigned short* __restrict__ wtlo,
    unsigned short* __restrict__ qhi, unsigned short* __restrict__ qlo) {
  __shared__ unsigned short xb[64 * 256];   // 32 KB, XOR-swizzled
  const int tid = threadIdx.x;
  const int lane = tid & 63;
  const int wv = tid >> 6;       // 0..3
  const int quad = lane >> 4;
  const int l16 = lane & 15;
  const int m0 = blockIdx.x * 64;

  short8 xhf[8], xlf[8];
#pragma unroll
  for (int s = 0; s < 2; ++s) {
    for (int c = tid; c < 64 * 64; c += 256) {   // 64 rows x 64 float4
      int row = c >> 6, c4 = c & 63;
      float4 v = *(const float4*)(x + (size_t)(m0 + row) * DD + c4 * 4);
      ushort4 o;
      if (s == 0) {
        o.x = f2bf(v.x); o.y = f2bf(v.y); o.z = f2bf(v.z); o.w = f2bf(v.w);
      } else {
        unsigned short h;
        h = f2bf(v.x); o.x = f2bf(v.x - bf2f(h));
        h = f2bf(v.y); o.y = f2bf(v.y - bf2f(h));
        h = f2bf(v.z); o.z = f2bf(v.z - bf2f(h));
        h = f2bf(v.w); o.w = f2bf(v.w - bf2f(h));
      }
      *(ushort4*)(xb + row * 256 + (((c4 >> 1) ^ (row & 7)) * 8) + (c4 & 1) * 4) = o;
    }
    __syncthreads();
    {
      int r = wv * 16 + l16;
#pragma unroll
      for (int c = 0; c < 8; ++c) {
        short8 v = *(const short8*)(xb + r * 256 + (((4 * c + quad) ^ (r & 7)) * 8));
        if (s == 0) xhf[c] = v; else xlf[c] = v;
      }
    }
    __syncthreads();
  }

#pragma unroll 1
  for (int et = 0; et < 16; ++et) {
    int e0 = et * 16;
    f32x4 acc; acc[0] = acc[1] = acc[2] = acc[3] = 0.f;
#pragma unroll
    for (int c = 0; c < 8; ++c) {
      short8 wh = *(const short8*)((const short*)wthi + (size_t)(e0 + l16) * DD + c * 32 + quad * 8);
      short8 wl = *(const short8*)((const short*)wtlo + (size_t)(e0 + l16) * DD + c * 32 + quad * 8);
      acc = __builtin_amdgcn_mfma_f32_16x16x32_bf16(xhf[c], wh, acc, 0, 0, 0);
      acc = __builtin_amdgcn_mfma_f32_16x16x32_bf16(xlf[c], wh, acc, 0, 0, 0);
      acc = __builtin_amdgcn_mfma_f32_16x16x32_bf16(xhf[c], wl, acc, 0, 0, 0);
    }
#pragma unroll
    for (int rg = 0; rg < 4; ++rg) {
      float q = acc[rg];
      unsigned short h = f2bf(q);
      unsigned short l = f2bf(q - bf2f(h));
      size_t off = (size_t)(m0 + wv * 16 + 4 * quad + rg) * DD + e0 + l16;
      qhi[off] = h; qlo[off] = l;
    }
  }
}

// ---------------- flash attention ----------------
// 8 waves x 16 q-rows (QBLK=128), KVBLK=32, swapped QK^T (S^T = K*Q^T),
// split-bf16 scores, online softmax, P through swizzled LDS, V^T tiles.
__global__ __launch_bounds__(512, 2) void attn_kernel(
    const unsigned short* __restrict__ ahi, const unsigned short* __restrict__ alo,
    const unsigned short* __restrict__ vt,
    const unsigned short* __restrict__ qhi, const unsigned short* __restrict__ qlo,
    float* __restrict__ out) {
  __shared__ unsigned short smem[28672];     // 57.3 KB
  unsigned short* qstage = smem;             // [64][256] during Q phase
  unsigned short* khl = smem;                // [32][256]
  unsigned short* kll = smem + 8192;         // [32][256]
  unsigned short* vtl = smem + 16384;        // [256][32]
  unsigned short* pl  = smem + 24576;        // [128][32]

  const int tid = threadIdx.x;
  const int lane = tid & 63;
  const int wv = tid >> 6;       // 0..7
  const int quad = lane >> 4;
  const int l16 = lane & 15;

  int bx = blockIdx.x;
  int lbx = (bx & 7) * 32 + (bx >> 3);   // XCD-chunked swizzle (256 = 8*32)
  const int b = lbx >> 4;
  const int qt = lbx & 15;
  const int qbase = qt * 128;

  short8 qh[8], ql[8];
  // ---- stage Q (4 sub-phases through one 32 KB buffer) ----
  for (int half = 0; half < 2; ++half) {
#pragma unroll
    for (int s = 0; s < 2; ++s) {
      const unsigned short* src = s ? qlo : qhi;
      for (int c = tid; c < 2048; c += 512) {
        int row = c >> 5, c8 = c & 31;
        *(uint4*)(qstage + row * 256 + ((c8 ^ (row & 7)) * 8)) =
            *(const uint4*)(src + ((size_t)b * NI + qbase + half * 64 + row) * DD + c8 * 8);
      }
      __syncthreads();
      if ((wv >> 2) == half) {
        int r = (wv & 3) * 16 + l16;
#pragma unroll
        for (int c = 0; c < 8; ++c) {
          short8 v = *(const short8*)(qstage + r * 256 + (((4 * c + quad) ^ (r & 7)) * 8));
          if (s == 0) qh[c] = v; else ql[c] = v;
        }
      }
      __syncthreads();
    }
  }

  f32x4 acc[16];
#pragma unroll
  for (int i = 0; i < 16; ++i) { acc[i][0] = 0.f; acc[i][1] = 0.f; acc[i][2] = 0.f; acc[i][3] = 0.f; }
  float m_run = -1e30f, l_run = 0.f;

  const size_t abase = (size_t)b * NA * DD;
  const size_t vbase = (size_t)b * DD * NA;
  const int prow = wv * 16 + l16;

#pragma unroll 1
  for (int kt = 0; kt < NA / 32; ++kt) {
    const int jb = kt * 32;
    // ---- stage K hi/lo + V^T ----
    for (int c = tid; c < 1024; c += 512) {
      int row = c >> 5, c8 = c & 31;
      int soff = (c8 ^ (row & 7)) * 8;
      *(uint4*)(khl + row * 256 + soff) = *(const uint4*)(ahi + abase + (size_t)(jb + row) * DD + c8 * 8);
      *(uint4*)(kll + row * 256 + soff) = *(const uint4*)(alo + abase + (size_t)(jb + row) * DD + c8 * 8);
      int d = c >> 2, c4 = c & 3;
      *(uint4*)(vtl + d * 32 + ((c4 ^ ((d >> 1) & 3)) * 8)) =
          *(const uint4*)(vt + vbase + (size_t)d * NA + jb + c4 * 8);
    }
    __syncthreads();

    // ---- S^T = K * Q^T, split precision ----
    f32x4 st[2];
    st[0][0]=st[0][1]=st[0][2]=st[0][3]=0.f;
    st[1][0]=st[1][1]=st[1][2]=st[1][3]=0.f;
#pragma unroll
    for (int t = 0; t < 2; ++t) {
      int jr = t * 16 + l16;
#pragma unroll
      for (int c = 0; c < 8; ++c) {
        int off = jr * 256 + (((4 * c + quad) ^ (jr & 7)) * 8);
        short8 kh = *(const short8*)(khl + off);
        short8 klv = *(const short8*)(kll + off);
        st[t] = __builtin_amdgcn_mfma_f32_16x16x32_bf16(kh, qh[c], st[t], 0, 0, 0);
        st[t] = __builtin_amdgcn_mfma_f32_16x16x32_bf16(kh, ql[c], st[t], 0, 0, 0);
        st[t] = __builtin_amdgcn_mfma_f32_16x16x32_bf16(klv, qh[c], st[t], 0, 0, 0);
      }
    }

    // ---- online softmax (rows = l16; reduce over quad groups) ----
    float mt = fmaxf(fmaxf(fmaxf(st[0][0], st[0][1]), fmaxf(st[0][2], st[0][3])),
                     fmaxf(fmaxf(st[1][0], st[1][1]), fmaxf(st[1][2], st[1][3])));
    mt = fmaxf(mt, __shfl_xor(mt, 16));
    mt = fmaxf(mt, __shfl_xor(mt, 32));
    float m_new = fmaxf(m_run, mt);
    float scl = __expf(m_run - m_new);
    float ps = 0.f;
    float pvv[8];
#pragma unroll
    for (int t = 0; t < 2; ++t)
#pragma unroll
      for (int rg = 0; rg < 4; ++rg) {
        float p = __expf(st[t][rg] - m_new);
        pvv[t * 4 + rg] = p; ps += p;
      }
    ps += __shfl_xor(ps, 16);
    ps += __shfl_xor(ps, 32);
    l_run = l_run * scl + ps;
    m_run = m_new;

    // ---- write P (bf16, packed b64, swizzled) ----
#pragma unroll
    for (int t = 0; t < 2; ++t) {
      ushort4 pk;
      pk.x = f2bf(pvv[t * 4 + 0]); pk.y = f2bf(pvv[t * 4 + 1]);
      pk.z = f2bf(pvv[t * 4 + 2]); pk.w = f2bf(pvv[t * 4 + 3]);
      *(ushort4*)(pl + prow * 32 + (((2 * t + (quad >> 1)) ^ ((prow >> 1) & 3)) * 8) + (quad & 1) * 4) = pk;
    }

    // ---- rescale O ----
    float sc0 = __shfl(scl, 4 * quad + 0);
    float sc1 = __shfl(scl, 4 * quad + 1);
    float sc2 = __shfl(scl, 4 * quad + 2);
    float sc3 = __shfl(scl, 4 * quad + 3);
#pragma unroll
    for (int i = 0; i < 16; ++i) {
      acc[i][0] *= sc0; acc[i][1] *= sc1; acc[i][2] *= sc2; acc[i][3] *= sc3;
    }

    // ---- PV ----
    short8 pa = *(const short8*)(pl + prow * 32 + ((quad ^ ((prow >> 1) & 3)) * 8));
#pragma unroll
    for (int dt = 0; dt < 16; ++dt) {
      int dr = dt * 16 + l16;
      short8 vb = *(const short8*)(vtl + dr * 32 + ((quad ^ ((dr >> 1) & 3)) * 8));
      acc[dt] = __builtin_amdgcn_mfma_f32_16x16x32_bf16(pa, vb, acc[dt], 0, 0, 0);
    }
    __syncthreads();
  }

  // ---- epilogue: normalize + store ----
  float linv = 1.0f / l_run;
  float li0 = __shfl(linv, 4 * quad + 0);
  float li1 = __shfl(linv, 4 * quad + 1);
  float li2 = __shfl(linv, 4 * quad + 2);
  float li3 = __shfl(linv, 4 * quad + 3);
  size_t obase = ((size_t)b * NI + qbase + wv * 16) * DD;
#pragma unroll
  for (int dt = 0; dt < 16; ++dt) {
    int d = dt * 16 + l16;
    out[obase + (size_t)(4 * quad + 0) * DD + d] = acc[dt][0] * li0;
    out[obase + (size_t)(4 * quad + 1) * DD + d] = acc[dt][1] * li1;
    out[obase + (size_t)(4 * quad + 2) * DD + d] = acc[dt][2] * li2;
    out[obase + (size_t)(4 * quad + 3) * DD + d] = acc[dt][3] * li3;
  }
}

extern "C" void kernel_launch(void* const* d_in, const int* in_sizes, int n_in,
                              void* d_out, int out_size, void* d_ws, size_t ws_size,
                              hipStream_t stream) {
  const float* x = (const float*)d_in[0];        // [16,2048,256]
  const float* att = (const float*)d_in[1];      // [16,2048,256]
  const float* W = (const float*)d_in[2];        // [256,256]
  float* out = (float*)d_out;

  const size_t NE = (size_t)BB * NA * DD;        // 8388608
  unsigned short* w0   = (unsigned short*)d_ws;
  unsigned short* ahi  = w0;
  unsigned short* alo  = w0 + NE;
  unsigned short* vt   = w0 + 2 * NE;
  unsigned short* qhi  = w0 + 3 * NE;
  unsigned short* qlo  = w0 + 4 * NE;
  unsigned short* wthi = w0 + 5 * NE;
  unsigned short* wtlo = w0 + 5 * NE + (size_t)DD * DD;
  // total ws use: (5*NE + 2*DD*DD)*2 bytes ≈ 84.2 MB

  split_kernel<<<2048, 256, 0, stream>>>(att, ahi, alo);
  tv_kernel<<<2048, 256, 0, stream>>>(att, vt);
  tw_kernel<<<16, 256, 0, stream>>>(W, wthi, wtlo);
  qgemm_kernel<<<512, 256, 0, stream>>>(x, wthi, wtlo, qhi, qlo);
  attn_kernel<<<256, 512, 0, stream>>>(ahi, alo, vt, qhi, qlo, out);
}